// Round 2
// baseline (931.464 us; speedup 1.0000x reference)
//
#include <hip/hip_runtime.h>
#include <stdint.h>

#define N_TOK 16384
#define D_IN  2048
#define D_OUT 2048
#define NEXP  8

#define BM 128
#define BN 128
#define BK 32

typedef __attribute__((ext_vector_type(8))) short bf16x8;
typedef __attribute__((ext_vector_type(4))) float f32x4;
typedef __attribute__((ext_vector_type(4))) unsigned short u16x4;

static __device__ __forceinline__ unsigned short f2bf(float x) {
  unsigned u = __builtin_bit_cast(unsigned, x);
  u += 0x7FFFu + ((u >> 16) & 1u);   // round-to-nearest-even
  return (unsigned short)(u >> 16);
}
static __device__ __forceinline__ float bf2f(unsigned short h) {
  unsigned u = ((unsigned)h) << 16;
  return __builtin_bit_cast(float, u);
}

// ---------------- routing ----------------
__global__ void zero_cnt(int* cnt) {
  if (threadIdx.x < NEXP) cnt[threadIdx.x] = 0;
}

__global__ void route_kernel(const int* __restrict__ idxs, int* __restrict__ cnt,
                             int* __restrict__ bucket) {
  int t = blockIdx.x * blockDim.x + threadIdx.x;
  if (t < N_TOK) {
    int e = idxs[t];
    int slot = atomicAdd(&cnt[e], 1);
    bucket[e * N_TOK + slot] = t;
  }
}

// ---------------- fp32 -> bf16 hi/lo split ----------------
__global__ void split_kernel(const float* __restrict__ in, unsigned short* __restrict__ hi,
                             unsigned short* __restrict__ lo, int n4) {
  int i = blockIdx.x * blockDim.x + threadIdx.x;
  int stride = gridDim.x * blockDim.x;
  const float4* in4 = (const float4*)in;
  for (; i < n4; i += stride) {
    float4 v = in4[i];
    float f[4] = {v.x, v.y, v.z, v.w};
    u16x4 h, l;
#pragma unroll
    for (int j = 0; j < 4; ++j) {
      unsigned short hh = f2bf(f[j]);
      h[j] = hh;
      l[j] = f2bf(f[j] - bf2f(hh));
    }
    *(u16x4*)(hi + (size_t)i * 4) = h;
    *(u16x4*)(lo + (size_t)i * 4) = l;
  }
}

// ---------------- grouped gather-GEMM (m97 structure, 3-term bf16 split) ----------------
#define GLD16(g, l)                                                                       \
  __builtin_amdgcn_global_load_lds((const __attribute__((address_space(1))) void*)(g),    \
                                   (__attribute__((address_space(3))) void*)(l), 16, 0, 0)

__global__ __launch_bounds__(256)
void moe_gemm(const unsigned short* __restrict__ xhi, const unsigned short* __restrict__ xlo,
              const unsigned short* __restrict__ whi, const unsigned short* __restrict__ wlo,
              const float* __restrict__ bias, const int* __restrict__ cnt,
              const int* __restrict__ bucket, float* __restrict__ out) {
  const int e = blockIdx.z;
  const int count = cnt[e];
  const int m0 = blockIdx.y * BM;
  if (m0 >= count) return;
  const int n0 = blockIdx.x * BN;

  __shared__ __align__(16) unsigned short sAh[BM * BK];
  __shared__ __align__(16) unsigned short sAl[BM * BK];
  __shared__ __align__(16) unsigned short sBh[BN * BK];
  __shared__ __align__(16) unsigned short sBl[BN * BK];
  __shared__ int rowtok[BM];

  const int tid = threadIdx.x;
  const int lane = tid & 63;
  const int wave = tid >> 6;

  if (tid < BM) {
    int r = m0 + tid;
    rowtok[tid] = bucket[e * N_TOK + (r < count ? r : count - 1)];
  }
  __syncthreads();

  // staging geometry: 512 segments of 16B per 8KB tile; seg s -> row s>>2, 16B chunk s&3
  const int s0 = tid;        // round 0
  const int s1 = 256 + tid;  // round 1
  const int row0 = s0 >> 2, seg0 = s0 & 3;
  const int row1 = s1 >> 2, seg1 = s1 & 3;
  const int tok0 = rowtok[row0];
  const int tok1 = rowtok[row1];
  const size_t aOff0 = (size_t)tok0 * D_IN + seg0 * 8;
  const size_t aOff1 = (size_t)tok1 * D_IN + seg1 * 8;
  const size_t bOff0 = (size_t)(n0 + row0) * D_IN + seg0 * 8;
  const size_t bOff1 = (size_t)(n0 + row1) * D_IN + seg1 * 8;
  const unsigned short* wBh = whi + (size_t)e * D_OUT * D_IN;
  const unsigned short* wBl = wlo + (size_t)e * D_OUT * D_IN;
  const int lb0 = wave * 1024;         // (wave*64)*16 bytes
  const int lb1 = 4096 + wave * 1024;  // (256 + wave*64)*16 bytes

  f32x4 acc[4][4];
#pragma unroll
  for (int i = 0; i < 4; ++i)
#pragma unroll
    for (int j = 0; j < 4; ++j) acc[i][j] = (f32x4)0.0f;

  const int r16 = lane & 15;
  const int ko = (lane >> 4) * 8;
  const int wm = (wave >> 1) * 64;
  const int wn = (wave & 1) * 64;

  for (int kt = 0; kt < D_IN; kt += BK) {
    __syncthreads();  // previous compute done before LDS overwrite
    GLD16(xhi + aOff0 + kt, (char*)sAh + lb0);
    GLD16(xhi + aOff1 + kt, (char*)sAh + lb1);
    GLD16(xlo + aOff0 + kt, (char*)sAl + lb0);
    GLD16(xlo + aOff1 + kt, (char*)sAl + lb1);
    GLD16(wBh + bOff0 + kt, (char*)sBh + lb0);
    GLD16(wBh + bOff1 + kt, (char*)sBh + lb1);
    GLD16(wBl + bOff0 + kt, (char*)sBl + lb0);
    GLD16(wBl + bOff1 + kt, (char*)sBl + lb1);
    __syncthreads();  // staging visible (compiler drains vmcnt before barrier)

    bf16x8 ah[4], al[4], bh[4], bl[4];
#pragma unroll
    for (int i = 0; i < 4; ++i) {
      ah[i] = *(const bf16x8*)&sAh[(wm + i * 16 + r16) * BK + ko];
      al[i] = *(const bf16x8*)&sAl[(wm + i * 16 + r16) * BK + ko];
      bh[i] = *(const bf16x8*)&sBh[(wn + i * 16 + r16) * BK + ko];
      bl[i] = *(const bf16x8*)&sBl[(wn + i * 16 + r16) * BK + ko];
    }
#pragma unroll
    for (int mi = 0; mi < 4; ++mi)
#pragma unroll
      for (int ni = 0; ni < 4; ++ni) {
        acc[mi][ni] = __builtin_amdgcn_mfma_f32_16x16x32_bf16(ah[mi], bh[ni], acc[mi][ni], 0, 0, 0);
        acc[mi][ni] = __builtin_amdgcn_mfma_f32_16x16x32_bf16(ah[mi], bl[ni], acc[mi][ni], 0, 0, 0);
        acc[mi][ni] = __builtin_amdgcn_mfma_f32_16x16x32_bf16(al[mi], bh[ni], acc[mi][ni], 0, 0, 0);
      }
  }

  // epilogue: bias + ReLU + scatter to original token rows
  const int rbase = (lane >> 4) * 4;
#pragma unroll
  for (int ni = 0; ni < 4; ++ni) {
    const int gn = n0 + wn + ni * 16 + r16;
    const float bv = bias[e * D_OUT + gn];
#pragma unroll
    for (int mi = 0; mi < 4; ++mi) {
#pragma unroll
      for (int i = 0; i < 4; ++i) {
        const int lr = wm + mi * 16 + rbase + i;  // local row in tile
        if (m0 + lr < count) {
          const int tok = rowtok[lr];
          out[(size_t)tok * D_OUT + gn] = fmaxf(acc[mi][ni][i] + bv, 0.0f);
        }
      }
    }
  }
}

// ---------------- slow-but-correct fallback (only if ws too small) ----------------
__global__ void fallback_kernel(const float* __restrict__ x, const int* __restrict__ idxs,
                                const float* __restrict__ W, const float* __restrict__ b,
                                float* __restrict__ out) {
  const int row = blockIdx.y;
  const int col = blockIdx.x * 256 + threadIdx.x;
  const int e = idxs[row];
  const float4* xr = (const float4*)(x + (size_t)row * D_IN);
  const float4* wr = (const float4*)(W + ((size_t)e * D_OUT + col) * D_IN);
  float acc = 0.f;
  for (int k = 0; k < D_IN / 4; ++k) {
    float4 a = xr[k], w = wr[k];
    acc += a.x * w.x + a.y * w.y + a.z * w.z + a.w * w.w;
  }
  out[(size_t)row * D_OUT + col] = fmaxf(acc + b[e * D_OUT + col], 0.0f);
}

extern "C" void kernel_launch(void* const* d_in, const int* in_sizes, int n_in,
                              void* d_out, int out_size, void* d_ws, size_t ws_size,
                              hipStream_t stream) {
  const float* x = (const float*)d_in[0];
  const int* idxs = (const int*)d_in[1];
  const float* W = (const float*)d_in[2];
  const float* b = (const float*)d_in[3];
  float* out = (float*)d_out;

  size_t off = 0;
  auto alloc = [&](size_t bytes) {
    void* p = (char*)d_ws + off;
    off += (bytes + 255) & ~(size_t)255;
    return p;
  };
  int* cnt = (int*)alloc(NEXP * sizeof(int));
  int* bucket = (int*)alloc((size_t)NEXP * N_TOK * sizeof(int));
  unsigned short* xhi = (unsigned short*)alloc((size_t)N_TOK * D_IN * 2);
  unsigned short* xlo = (unsigned short*)alloc((size_t)N_TOK * D_IN * 2);
  unsigned short* whi = (unsigned short*)alloc((size_t)NEXP * D_OUT * D_IN * 2);
  unsigned short* wlo = (unsigned short*)alloc((size_t)NEXP * D_OUT * D_IN * 2);

  if (off > ws_size) {
    // workspace too small: correct-but-slow path
    dim3 g(D_OUT / 256, N_TOK, 1);
    fallback_kernel<<<g, 256, 0, stream>>>(x, idxs, W, b, out);
    return;
  }

  zero_cnt<<<1, 64, 0, stream>>>(cnt);
  route_kernel<<<(N_TOK + 255) / 256, 256, 0, stream>>>(idxs, cnt, bucket);

  const int n4x = N_TOK * D_IN / 4;        // 8,388,608
  const int n4w = NEXP * D_OUT * D_IN / 4; // 8,388,608
  split_kernel<<<2048, 256, 0, stream>>>(x, xhi, xlo, n4x);
  split_kernel<<<2048, 256, 0, stream>>>(W, whi, wlo, n4w);

  dim3 grid(D_OUT / BN, (N_TOK + BM - 1) / BM, NEXP);
  moe_gemm<<<grid, 256, 0, stream>>>(xhi, xlo, whi, wlo, b, cnt, bucket, out);
}

// Round 3
// 847.249 us; speedup vs baseline: 1.0994x; 1.0994x over previous
//
#include <hip/hip_runtime.h>
#include <stdint.h>

#define N_TOK 16384
#define D_IN  2048
#define D_OUT 2048
#define NEXP  8

#define BM 256
#define BN 256
#define BK 32
#define NKT (D_IN / BK)  // 64 K-tiles

typedef __attribute__((ext_vector_type(8))) short bf16x8;
typedef __attribute__((ext_vector_type(4))) float f32x4;
typedef __attribute__((ext_vector_type(4))) unsigned short u16x4;

static __device__ __forceinline__ unsigned short f2bf(float x) {
  unsigned u = __builtin_bit_cast(unsigned, x);
  u += 0x7FFFu + ((u >> 16) & 1u);  // round-to-nearest-even
  return (unsigned short)(u >> 16);
}
static __device__ __forceinline__ float bf2f(unsigned short h) {
  unsigned u = ((unsigned)h) << 16;
  return __builtin_bit_cast(float, u);
}

// ---------------- routing (per-block LDS histogram, G12) ----------------
__global__ void zero_cnt(int* cnt) {
  if (threadIdx.x < NEXP) cnt[threadIdx.x] = 0;
}

__global__ void route_kernel(const int* __restrict__ idxs, int* __restrict__ cnt,
                             int* __restrict__ bucket) {
  __shared__ int hist[NEXP];
  __shared__ int base[NEXP];
  __shared__ int pos[NEXP];
  const int t = blockIdx.x * 256 + threadIdx.x;  // N_TOK % 256 == 0
  if (threadIdx.x < NEXP) { hist[threadIdx.x] = 0; pos[threadIdx.x] = 0; }
  __syncthreads();
  const int e = idxs[t];
  atomicAdd(&hist[e], 1);  // LDS atomic
  __syncthreads();
  if (threadIdx.x < NEXP)
    base[threadIdx.x] = atomicAdd(&cnt[threadIdx.x], hist[threadIdx.x]);  // 8 global atomics/block
  __syncthreads();
  const int r = atomicAdd(&pos[e], 1);  // LDS atomic
  bucket[e * N_TOK + base[e] + r] = t;
}

// ---------------- fp32 -> bf16 hi/lo split ----------------
__global__ void split_kernel(const float* __restrict__ in, unsigned short* __restrict__ hi,
                             unsigned short* __restrict__ lo, int n4) {
  int i = blockIdx.x * blockDim.x + threadIdx.x;
  int stride = gridDim.x * blockDim.x;
  const float4* in4 = (const float4*)in;
  for (; i < n4; i += stride) {
    float4 v = in4[i];
    float f[4] = {v.x, v.y, v.z, v.w};
    u16x4 h, l;
#pragma unroll
    for (int j = 0; j < 4; ++j) {
      unsigned short hh = f2bf(f[j]);
      h[j] = hh;
      l[j] = f2bf(f[j] - bf2f(hh));
    }
    *(u16x4*)(hi + (size_t)i * 4) = h;
    *(u16x4*)(lo + (size_t)i * 4) = l;
  }
}

// ---------------- grouped gather-GEMM: 256x256 tile, 4-phase schedule ----------------
// LDS buffer layout (per 64KB buffer): bytes [0,32K) = A-tile, [32K,64K) = B-tile.
// Tile row r (0..255) is 128B = [hi k0..31 | lo k0..31], 16B chunks XOR-swizzled:
// phys_chunk = logical_chunk ^ (r & 7). Staged via global_load_lds (linear LDS dest,
// inverse-swizzled per-lane global source — rule #21).
#define GLD16(g, l)                                                                    \
  __builtin_amdgcn_global_load_lds((const __attribute__((address_space(1))) void*)(g), \
                                   (__attribute__((address_space(3))) void*)(l), 16, 0, 0)
#define SB() __builtin_amdgcn_sched_barrier(0)
#define BAR() __builtin_amdgcn_s_barrier()

template <int MH>
static __device__ __forceinline__ void loadA(const char* rb, int wr, int off0,
                                             bf16x8 (&afr)[4][2]) {
#pragma unroll
  for (int mf = 0; mf < 4; ++mf) {
    const int ro = (wr * 128 + MH * 64 + mf * 16) * 128;
    afr[mf][0] = *(const bf16x8*)(rb + ro + off0);
    afr[mf][1] = *(const bf16x8*)(rb + ro + (off0 ^ 64));  // lo-half: chunk ^= 4
  }
}

template <int NH>
static __device__ __forceinline__ void loadB(const char* rb, int wc, int off0,
                                             bf16x8 (&bfr)[2][2]) {
#pragma unroll
  for (int nf = 0; nf < 2; ++nf) {
    const int ro = 32768 + (wc * 64 + NH * 32 + nf * 16) * 128;
    bfr[nf][0] = *(const bf16x8*)(rb + ro + off0);
    bfr[nf][1] = *(const bf16x8*)(rb + ro + (off0 ^ 64));
  }
}

template <int MH, int NH>
static __device__ __forceinline__ void mfma24(bf16x8 (&afr)[4][2], bf16x8 (&bfr)[2][2],
                                              f32x4 (&acc)[8][4]) {
#pragma unroll
  for (int mf = 0; mf < 4; ++mf)
#pragma unroll
    for (int nf = 0; nf < 2; ++nf) {
      f32x4 a = acc[MH * 4 + mf][NH * 2 + nf];
      a = __builtin_amdgcn_mfma_f32_16x16x32_bf16(afr[mf][0], bfr[nf][0], a, 0, 0, 0);  // hi*hi
      a = __builtin_amdgcn_mfma_f32_16x16x32_bf16(afr[mf][0], bfr[nf][1], a, 0, 0, 0);  // hi*lo
      a = __builtin_amdgcn_mfma_f32_16x16x32_bf16(afr[mf][1], bfr[nf][0], a, 0, 0, 0);  // lo*hi
      acc[MH * 4 + mf][NH * 2 + nf] = a;
    }
}

__global__ __launch_bounds__(512, 2)
void moe_gemm(const unsigned short* __restrict__ xhi, const unsigned short* __restrict__ xlo,
              const unsigned short* __restrict__ whi, const unsigned short* __restrict__ wlo,
              const float* __restrict__ bias, const int* __restrict__ cnt,
              const int* __restrict__ bucket, float* __restrict__ out) {
  const int e = blockIdx.z;
  const int count = cnt[e];
  const int m0 = blockIdx.y * BM;
  if (m0 >= count) return;  // uniform early exit, before any barrier
  const int n0 = blockIdx.x * BN;

  __shared__ __align__(16) char sbuf[2][65536];
  __shared__ int rowtok[BM];

  const int tid = threadIdx.x;
  const int lane = tid & 63;
  const int w = tid >> 6;
  const int wr = w >> 2;  // 0..1  (wave row: 128 rows each)
  const int wc = w & 3;   // 0..3  (wave col: 64 cols each)

  if (tid < BM) {
    int r = m0 + tid;
    rowtok[tid] = bucket[e * N_TOK + (r < count ? r : count - 1)];
  }
  __syncthreads();

  // Per-thread staging sources for the 8 rounds (q) of one 64KB K-tile buffer.
  // Round q, thread t writes LDS linear offset o = q*8192 + t*16.
  // Decompose: region A (q<4) / B (q>=4); row r = (q&3)*64 + (t>>3);
  // phys chunk = t&7; logical chunk c = (t&7) ^ (r&7); half = c>>2 (hi/lo); kc = c&3.
  const unsigned short* whiE = whi + (size_t)e * D_OUT * D_IN;
  const unsigned short* wloE = wlo + (size_t)e * D_OUT * D_IN;
  const unsigned short* srcb[8];
#pragma unroll
  for (int q = 0; q < 8; ++q) {
    const int r = (q & 3) * 64 + (tid >> 3);
    const int c = (tid & 7) ^ ((tid >> 3) & 7);
    const int half = c >> 2, kc = c & 3;
    if (q < 4) {
      const int tok = rowtok[r];
      srcb[q] = (half ? xlo : xhi) + (size_t)tok * D_IN + kc * 8;
    } else {
      srcb[q] = (half ? wloE : whiE) + (size_t)(n0 + r) * D_IN + kc * 8;
    }
  }
  const int dstoff = w * 1024;  // wave-uniform LDS dest base (+ lane*16 implicit)

  // ds-read per-lane byte offset within a frag row-group:
  // row = R0 + (lane&15)  (R0 multiple of 16 => row&7 == lane&7)
  // logical chunk = hl*4 + (lane>>4); phys = chunk ^ (lane&7)
  const int off0 = (lane & 15) * 128 + (((lane >> 4) ^ (lane & 7)) * 16);

  f32x4 acc[8][4];
#pragma unroll
  for (int i = 0; i < 8; ++i)
#pragma unroll
    for (int j = 0; j < 4; ++j) acc[i][j] = (f32x4)0.0f;
  bf16x8 afr[4][2], bfr[2][2];

  // Prologue: stage K-tile 0 into buffer 0, drain, barrier.
  {
    char* wb = sbuf[0];
#pragma unroll
    for (int q = 0; q < 8; ++q) GLD16(srcb[q], wb + q * 8192 + dstoff);
  }
  asm volatile("s_waitcnt vmcnt(0)" ::: "memory");
  SB(); BAR(); SB();

  int cur = 0;
  for (int i = 0; i < NKT; ++i) {
    const char* rb = sbuf[cur];
    char* wb = sbuf[cur ^ 1];
    const int ktn = (i + 1) * BK;
    const bool nx = (i + 1 < NKT);

    // phase 0: A(mh0)+B(nh0) frags | stage rounds 0,1
    loadA<0>(rb, wr, off0, afr);
    loadB<0>(rb, wc, off0, bfr);
    if (nx) { GLD16(srcb[0] + ktn, wb + 0 * 8192 + dstoff); GLD16(srcb[1] + ktn, wb + 1 * 8192 + dstoff); }
    SB(); BAR(); SB();
    __builtin_amdgcn_s_setprio(1); mfma24<0, 0>(afr, bfr, acc); __builtin_amdgcn_s_setprio(0);
    SB(); BAR(); SB();

    // phase 1: B(nh1) | stage rounds 2,3
    loadB<1>(rb, wc, off0, bfr);
    if (nx) { GLD16(srcb[2] + ktn, wb + 2 * 8192 + dstoff); GLD16(srcb[3] + ktn, wb + 3 * 8192 + dstoff); }
    SB(); BAR(); SB();
    __builtin_amdgcn_s_setprio(1); mfma24<0, 1>(afr, bfr, acc); __builtin_amdgcn_s_setprio(0);
    SB(); BAR(); SB();

    // phase 2: A(mh1)+B(nh0) | stage rounds 4,5
    loadA<1>(rb, wr, off0, afr);
    loadB<0>(rb, wc, off0, bfr);
    if (nx) { GLD16(srcb[4] + ktn, wb + 4 * 8192 + dstoff); GLD16(srcb[5] + ktn, wb + 5 * 8192 + dstoff); }
    SB(); BAR(); SB();
    __builtin_amdgcn_s_setprio(1); mfma24<1, 0>(afr, bfr, acc); __builtin_amdgcn_s_setprio(0);
    SB(); BAR(); SB();

    // phase 3: B(nh1) | stage rounds 6,7
    loadB<1>(rb, wc, off0, bfr);
    if (nx) { GLD16(srcb[6] + ktn, wb + 6 * 8192 + dstoff); GLD16(srcb[7] + ktn, wb + 7 * 8192 + dstoff); }
    SB(); BAR(); SB();
    __builtin_amdgcn_s_setprio(1); mfma24<1, 1>(afr, bfr, acc); __builtin_amdgcn_s_setprio(0);
    // iteration close: all 8 staged loads for cur^1 must land before next iter reads it
    asm volatile("s_waitcnt vmcnt(0)" ::: "memory");
    SB(); BAR(); SB();
    cur ^= 1;
  }

  // epilogue: bias + ReLU + scatter (C/D layout: col=lane&15, row=(lane>>4)*4+i)
  const int r16 = lane & 15;
  const int rb4 = (lane >> 4) * 4;
#pragma unroll
  for (int n = 0; n < 4; ++n) {
    const int gn = n0 + wc * 64 + n * 16 + r16;
    const float bv = bias[e * D_OUT + gn];
#pragma unroll
    for (int m = 0; m < 8; ++m) {
      const int lr = wr * 128 + m * 16 + rb4;
#pragma unroll
      for (int i2 = 0; i2 < 4; ++i2) {
        const int row = lr + i2;
        if (m0 + row < count) {
          out[(size_t)rowtok[row] * D_OUT + gn] = fmaxf(acc[m][n][i2] + bv, 0.0f);
        }
      }
    }
  }
}

// ---------------- slow-but-correct fallback (only if ws too small) ----------------
__global__ void fallback_kernel(const float* __restrict__ x, const int* __restrict__ idxs,
                                const float* __restrict__ W, const float* __restrict__ b,
                                float* __restrict__ out) {
  const int row = blockIdx.y;
  const int col = blockIdx.x * 256 + threadIdx.x;
  const int e = idxs[row];
  const float4* xr = (const float4*)(x + (size_t)row * D_IN);
  const float4* wr = (const float4*)(W + ((size_t)e * D_OUT + col) * D_IN);
  float acc = 0.f;
  for (int k = 0; k < D_IN / 4; ++k) {
    float4 a = xr[k], w = wr[k];
    acc += a.x * w.x + a.y * w.y + a.z * w.z + a.w * w.w;
  }
  out[(size_t)row * D_OUT + col] = fmaxf(acc + b[e * D_OUT + col], 0.0f);
}

extern "C" void kernel_launch(void* const* d_in, const int* in_sizes, int n_in,
                              void* d_out, int out_size, void* d_ws, size_t ws_size,
                              hipStream_t stream) {
  const float* x = (const float*)d_in[0];
  const int* idxs = (const int*)d_in[1];
  const float* W = (const float*)d_in[2];
  const float* b = (const float*)d_in[3];
  float* out = (float*)d_out;

  size_t off = 0;
  auto alloc = [&](size_t bytes) {
    void* p = (char*)d_ws + off;
    off += (bytes + 255) & ~(size_t)255;
    return p;
  };
  int* cnt = (int*)alloc(NEXP * sizeof(int));
  int* bucket = (int*)alloc((size_t)NEXP * N_TOK * sizeof(int));
  unsigned short* xhi = (unsigned short*)alloc((size_t)N_TOK * D_IN * 2);
  unsigned short* xlo = (unsigned short*)alloc((size_t)N_TOK * D_IN * 2);
  unsigned short* whi = (unsigned short*)alloc((size_t)NEXP * D_OUT * D_IN * 2);
  unsigned short* wlo = (unsigned short*)alloc((size_t)NEXP * D_OUT * D_IN * 2);

  if (off > ws_size) {
    dim3 g(D_OUT / 256, N_TOK, 1);
    fallback_kernel<<<g, 256, 0, stream>>>(x, idxs, W, b, out);
    return;
  }

  zero_cnt<<<1, 64, 0, stream>>>(cnt);
  route_kernel<<<N_TOK / 256, 256, 0, stream>>>(idxs, cnt, bucket);

  const int n4x = N_TOK * D_IN / 4;
  const int n4w = NEXP * D_OUT * D_IN / 4;
  split_kernel<<<2048, 256, 0, stream>>>(x, xhi, xlo, n4x);
  split_kernel<<<2048, 256, 0, stream>>>(W, whi, wlo, n4w);

  dim3 grid(D_OUT / BN, N_TOK / BM, NEXP);
  moe_gemm<<<grid, 512, 0, stream>>>(xhi, xlo, whi, wlo, b, cnt, bucket, out);
}